// Round 23
// baseline (320.143 us; speedup 1.0000x reference)
//
#include <hip/hip_runtime.h>
#include <hip/hip_bf16.h>

typedef unsigned short u16;
typedef __attribute__((ext_vector_type(8))) short bf16x8;
typedef __attribute__((ext_vector_type(4))) float f32x4;
typedef __attribute__((ext_vector_type(8))) u16 u16x8;
typedef __attribute__((ext_vector_type(4))) u16 u16x4;

#define T_SEQ 2048
#define HID 4096
#define NQ 32
#define NKV 8
#define DH 128
#define WIN 1024

__device__ __forceinline__ u16 f2bf(float f) {
  union { float f; unsigned int u; } v; v.f = f;
  unsigned int u = v.u;
  unsigned int r = (u + 0x7FFFu + ((u >> 16) & 1u)) >> 16;
  return (u16)r;
}
__device__ __forceinline__ float bf2f(u16 b) {
  union { unsigned int u; float f; } v; v.u = ((unsigned int)b) << 16;
  return v.f;
}

__device__ __forceinline__ void gload16(const void* g, void* l) {
  __builtin_amdgcn_global_load_lds(
      (const __attribute__((address_space(1))) unsigned int*)g,
      (__attribute__((address_space(3))) unsigned int*)l, 16, 0, 0);
}

// ---------------- elementwise f32 -> bf16 ----------------
__global__ __launch_bounds__(256) void f32_to_bf16(const float* __restrict__ in,
                                                   u16* __restrict__ out, int n) {
  int i = (blockIdx.x * 256 + threadIdx.x) * 8;
  if (i >= n) return;
  float4 a = *(const float4*)(in + i);
  float4 b = *(const float4*)(in + i + 4);
  u16x8 r;
  r[0] = f2bf(a.x); r[1] = f2bf(a.y); r[2] = f2bf(a.z); r[3] = f2bf(a.w);
  r[4] = f2bf(b.x); r[5] = f2bf(b.y); r[6] = f2bf(b.z); r[7] = f2bf(b.w);
  *(u16x8*)(out + i) = r;
}

// ---------------- tiled transpose f32 (R x C) -> bf16 (C x R), 64x64 float4 ----------------
__global__ __launch_bounds__(256) void transpose_f32_to_bf16(const float* __restrict__ in,
                                                             u16* __restrict__ out,
                                                             int R, int C) {
  __shared__ float tile[64][65];
  int c0 = blockIdx.x * 64, r0 = blockIdx.y * 64;
  int tx = threadIdx.x, ty = threadIdx.y;    // 16 x 16
#pragma unroll
  for (int i = 0; i < 64; i += 16) {
    float4 v = *(const float4*)(in + (size_t)(r0 + ty + i) * C + c0 + tx * 4);
    tile[ty + i][tx * 4 + 0] = v.x;
    tile[ty + i][tx * 4 + 1] = v.y;
    tile[ty + i][tx * 4 + 2] = v.z;
    tile[ty + i][tx * 4 + 3] = v.w;
  }
  __syncthreads();
#pragma unroll
  for (int i = 0; i < 64; i += 16) {
    u16x4 o;
#pragma unroll
    for (int j = 0; j < 4; ++j) o[j] = f2bf(tile[tx * 4 + j][ty + i]);
    *(u16x4*)(out + (size_t)(c0 + ty + i) * R + r0 + tx * 4) = o;
  }
}

// ---------------- bf16 transpose for V: Vn[2048][1024] -> Vt[1024][2048] ----------------
__global__ __launch_bounds__(256) void v_transpose(const u16* __restrict__ Vn,
                                                   u16* __restrict__ Vt) {
  __shared__ u16 tile[64][68];
  int tx = threadIdx.x & 15, ty = threadIdx.x >> 4;   // 16 x 16
  int t0 = blockIdx.x * 64, dh0 = blockIdx.y * 64;
#pragma unroll
  for (int i = 0; i < 64; i += 16) {
    u16x4 v = *(const u16x4*)(Vn + (size_t)(t0 + ty + i) * 1024 + dh0 + tx * 4);
    tile[ty + i][tx * 4 + 0] = v[0];
    tile[ty + i][tx * 4 + 1] = v[1];
    tile[ty + i][tx * 4 + 2] = v[2];
    tile[ty + i][tx * 4 + 3] = v[3];
  }
  __syncthreads();
#pragma unroll
  for (int i = 0; i < 64; i += 16) {
    u16x4 o;
#pragma unroll
    for (int j = 0; j < 4; ++j) o[j] = tile[tx * 4 + j][ty + i];
    *(u16x4*)(Vt + (size_t)(dh0 + ty + i) * 2048 + t0 + tx * 4) = o;
  }
}

// ---------------- gemm_hw: 128x128 BK=32 1-window GEMM, 3 blocks/CU (R22, gemm1) --------
// The untested lever from the R18 audit: waves/SIMD 2 -> 3 on the proven
// 1-window template. 4 waves 2Mx2N (per-wave 64x64 = 4mf x 4nf, 16 MFMA/tile,
// single-ks frags since BK=32 = MFMA K). LDS 40KB (A 2x8KB, B 3-ring x 8KB)
// -> 768 blocks at 16x48 tiles = 3 blocks/CU = 12 waves/CU = 3 waves/SIMD;
// co-resident blocks cover each other's vmcnt/barrier/LDS stalls (m114).
// Window(t): rd afA[4](slot t&1) + bfr[4](slot t%3) | stage A(t+1)->(t+1)&1 x2
//   | stage B(t+2)->(t+2)%3 x2 | setprio | 16 MFMA | lgkm0 | vmcnt(2) | barrier.
// vmcnt: start outstanding = B(t+1)x2; +A(t+1)x2 +B(t+2)x2 = 6; vmcnt(2)
//   retires B(t+1)+A(t+1), keeps B(t+2). Prologue A0,B0,B1 (6) + vmcnt(2).
// Slot hazards: stage targets {(t+1)&1,(t+2)%3} disjoint from read slots
//   {t&1,t%3}; last readers ended >=1 barrier earlier. Tail clamps (dummies).
// Swizzle for 64B rows (4 chunks): swz(r)=(r>>1)&3 both sides (R8-verified:
//   16 lanes cover all 8 slots = free 2-way).
template <bool BF16OUT>
__global__ __launch_bounds__(256, 3) void gemm_hw(const u16* __restrict__ A,
                                                  const u16* __restrict__ Bt,
                                                  void* __restrict__ Cv,
                                                  int N, int K, int NT) {
  __shared__ u16 lsA[2][4096];    // 2 x 8KB (128 rows x 32 k)
  __shared__ u16 lsB[3][4096];    // 3 x 8KB
  const int tid = threadIdx.x;
  const int lane = tid & 63, w = tid >> 6;     // 4 waves
  const int wm = w >> 1, wn = w & 1;           // 2M x 2N
  const int l15 = lane & 15, l4 = lane >> 4;

  const int nwg = gridDim.x;                   // % 8 == 0
  const int cpx = nwg >> 3;
  const int bid = blockIdx.x;
  const int swz = (bid & 7) * cpx + (bid >> 3);
  const int bm = (swz & 15) * 128;             // 16 M-tiles (x-major)
  const int bn = (swz >> 4) * 128;             // N-tiles

  auto stageA = [&](int unit, int slot, int kt) {
    int c = unit * 256 + tid;                  // 16B chunk 0..511
    int r = c >> 2, cp = c & 3;
    int scp = cp ^ ((r >> 1) & 3);             // pre-swizzled source chunk
    gload16(A + (size_t)(bm + r) * K + kt * 32 + scp * 8,
            (char*)lsA[slot] + c * 16);
  };
  auto stageB = [&](int unit, int slot, int kt) {
    int c = unit * 256 + tid;
    int r = c >> 2, cp = c & 3;
    int scp = cp ^ ((r >> 1) & 3);
    gload16(Bt + (size_t)(bn + r) * K + kt * 32 + scp * 8,
            (char*)lsB[slot] + c * 16);
  };
  auto rdA = [&](int slot, int mf) -> bf16x8 {
    int r = wm * 64 + mf * 16 + l15;
    int ch = l4 ^ ((r >> 1) & 3);
    return *(const bf16x8*)(lsA[slot] + r * 32 + ch * 8);
  };
  auto rdB = [&](int slot, int nf) -> bf16x8 {
    int r = wn * 64 + nf * 16 + l15;
    int ch = l4 ^ ((r >> 1) & 3);
    return *(const bf16x8*)(lsB[slot] + r * 32 + ch * 8);
  };

  f32x4 acc[4][4] = {};
  bf16x8 afA[4], bfr[4];

  // prologue: A(0)->s0 x2, B(0)->s0 x2, B(1)->s1 x2; vmcnt(2) -> tile0 resident
  stageA(0, 0, 0); stageA(1, 0, 0);
  stageB(0, 0, 0); stageB(1, 0, 0);
  stageB(0, 1, 1); stageB(1, 1, 1);
  asm volatile("s_waitcnt vmcnt(2)" ::: "memory");
  __builtin_amdgcn_s_barrier();

  for (int t = 0; t < NT; ++t) {
    const int sA = t & 1, sB = t % 3;
    const int ktA = (t + 1 < NT) ? t + 1 : NT - 1;
    const int ktB = (t + 2 < NT) ? t + 2 : NT - 1;

#pragma unroll
    for (int mf = 0; mf < 4; ++mf) afA[mf] = rdA(sA, mf);
#pragma unroll
    for (int nf = 0; nf < 4; ++nf) bfr[nf] = rdB(sB, nf);
    stageA(0, (t + 1) & 1, ktA); stageA(1, (t + 1) & 1, ktA);
    stageB(0, (t + 2) % 3, ktB); stageB(1, (t + 2) % 3, ktB);
    __builtin_amdgcn_s_setprio(1);
#pragma unroll
    for (int nf = 0; nf < 4; ++nf)             // nf outer: consume in read order
#pragma unroll
      for (int mf = 0; mf < 4; ++mf)
        acc[mf][nf] = __builtin_amdgcn_mfma_f32_16x16x32_bf16(afA[mf], bfr[nf], acc[mf][nf], 0, 0, 0);
    __builtin_amdgcn_s_setprio(0);
    asm volatile("s_waitcnt lgkmcnt(0)" ::: "memory");
    asm volatile("s_waitcnt vmcnt(2)" ::: "memory");   // tile t+1 resident
    __builtin_amdgcn_s_barrier();
  }

  asm volatile("s_waitcnt vmcnt(0)" ::: "memory");     // drain tail dummies

#pragma unroll
  for (int mi = 0; mi < 4; ++mi)
#pragma unroll
    for (int ni = 0; ni < 4; ++ni) {
      int row = bm + wm * 64 + mi * 16 + l4 * 4;
      int col = bn + wn * 64 + ni * 16 + l15;
      if constexpr (BF16OUT) {
        u16* dst = (u16*)Cv;
#pragma unroll
        for (int j = 0; j < 4; ++j)
          dst[(size_t)(row + j) * N + col] = f2bf(acc[mi][ni][j]);
      } else {
        float* p = (float*)Cv + (size_t)row * N + col;
        p[0] = acc[mi][ni][0];
        p[(size_t)N] = acc[mi][ni][1];
        p[2 * (size_t)N] = acc[mi][ni][2];
        p[3 * (size_t)N] = acc[mi][ni][3];
      }
    }
}

// ---------------- gemm_1w: 256xBN GEMM, ONE barrier/tile (kept for revert) ----------------
template <int NF, bool BF16OUT>
__global__ __launch_bounds__(512, 2) void gemm_1w(const u16* __restrict__ A,
                                                  const u16* __restrict__ Bt,
                                                  void* __restrict__ Cv,
                                                  int N, int K, int NT) {
  constexpr int HN = NF * 16;
  constexpr int BN = 4 * HN;
  constexpr int NB = BN / 64;
  __shared__ u16 lsA[2][16384];     // 2 x 32KB
  __shared__ u16 lsB[3][BN * 64];   // 3 x (BN*128B)
  const int tid = threadIdx.x;
  const int lane = tid & 63, w = tid >> 6;
  const int wm = w >> 1, wn = w & 1;           // 4M x 2N
  const int l15 = lane & 15, l4 = lane >> 4;

  const int nwg = gridDim.x;
  const int cpx = nwg >> 3;
  const int bid = blockIdx.x;
  const int swz = (bid & 7) * cpx + (bid >> 3);
  const int bm = (swz & 7) * 256;
  const int bn = (swz >> 3) * BN;

  auto stageA = [&](int unit, int slot, int kt) {
    int r = tid >> 3, cp = tid & 7;
    int scp = cp ^ (r & 7);
    gload16(A + (size_t)(bm + unit * 64 + r) * K + kt * 64 + scp * 8,
            (char*)lsA[slot] + (unit * 512 + tid) * 16);
  };
  auto stageB = [&](int unit, int slot, int kt) {
    int r = tid >> 3, cp = tid & 7;
    int scp = cp ^ (r & 7);
    gload16(Bt + (size_t)(bn + unit * 64 + r) * K + kt * 64 + scp * 8,
            (char*)lsB[slot] + (unit * 512 + tid) * 16);
  };
  auto rdA = [&](int slot, int mf, int ks) -> bf16x8 {
    int r = wm * 64 + mf * 16 + l15;
    int ch = (ks * 4 + l4) ^ (r & 7);
    return *(const bf16x8*)(lsA[slot] + r * 64 + ch * 8);
  };
  auto rdB = [&](int slot, int nf, int ks) -> bf16x8 {
    int r = wn * 2 * HN + nf * 16 + l15;
    int ch = (ks * 4 + l4) ^ (r & 7);
    return *(const bf16x8*)(lsB[slot] + r * 64 + ch * 8);
  };

#define WAIT_NB() do { if constexpr (NB == 3) asm volatile("s_waitcnt vmcnt(3)" ::: "memory"); \
                       else                   asm volatile("s_waitcnt vmcnt(2)" ::: "memory"); } while (0)

  f32x4 acc[4][2 * NF] = {};
  bf16x8 afA[4][2], bfr[2 * NF][2];

  stageA(0, 0, 0); stageA(1, 0, 0); stageA(2, 0, 0); stageA(3, 0, 0);
#pragma unroll
  for (int u = 0; u < NB; ++u) stageB(u, 0, 0);
#pragma unroll
  for (int u = 0; u < NB; ++u) stageB(u, 1, 1);
  WAIT_NB();
  __builtin_amdgcn_s_barrier();

  for (int t = 0; t < NT; ++t) {
    const int sA = t & 1, sB = t % 3;
    const int ktA = (t + 1 < NT) ? t + 1 : NT - 1;
    const int ktB = (t + 2 < NT) ? t + 2 : NT - 1;

#pragma unroll
    for (int mf = 0; mf < 4; ++mf)
#pragma unroll
      for (int ks = 0; ks < 2; ++ks) afA[mf][ks] = rdA(sA, mf, ks);
#pragma unroll
    for (int nf = 0; nf < 2 * NF; ++nf)
#pragma unroll
      for (int ks = 0; ks < 2; ++ks) bfr[nf][ks] = rdB(sB, nf, ks);
    stageA(0, (t + 1) & 1, ktA); stageA(1, (t + 1) & 1, ktA);
    stageA(2, (t + 1) & 1, ktA); stageA(3, (t + 1) & 1, ktA);
#pragma unroll
    for (int u = 0; u < NB; ++u) stageB(u, (t + 2) % 3, ktB);
    __builtin_amdgcn_s_setprio(1);
#pragma unroll
    for (int nf = 0; nf < 2 * NF; ++nf)        // nf OUTER: consume in read order
#pragma unroll
      for (int mf = 0; mf < 4; ++mf) {
        acc[mf][nf] = __builtin_amdgcn_mfma_f32_16x16x32_bf16(afA[mf][0], bfr[nf][0], acc[mf][nf], 0, 0, 0);
        acc[mf][nf] = __builtin_amdgcn_mfma_f32_16x16x32_bf16(afA[mf][1], bfr[nf][1], acc[mf][nf], 0, 0, 0);
      }
    __builtin_amdgcn_s_setprio(0);
    asm volatile("s_waitcnt lgkmcnt(0)" ::: "memory");
    WAIT_NB();
    __builtin_amdgcn_s_barrier();
  }

  asm volatile("s_waitcnt vmcnt(0)" ::: "memory");

#pragma unroll
  for (int mi = 0; mi < 4; ++mi)
#pragma unroll
    for (int ni = 0; ni < 2 * NF; ++ni) {
      int row = bm + wm * 64 + mi * 16 + l4 * 4;
      int col = bn + wn * 2 * HN + ni * 16 + l15;
      if constexpr (BF16OUT) {
        u16* dst = (u16*)Cv;
#pragma unroll
        for (int j = 0; j < 4; ++j)
          dst[(size_t)(row + j) * N + col] = f2bf(acc[mi][ni][j]);
      } else {
        float* p = (float*)Cv + (size_t)row * N + col;
        p[0] = acc[mi][ni][0];
        p[(size_t)N] = acc[mi][ni][1];
        p[2 * (size_t)N] = acc[mi][ni][2];
        p[3 * (size_t)N] = acc[mi][ni][3];
      }
    }
#undef WAIT_NB
}

// ---------------- gemm_1wh: 128x128 1-window GEMM, 4 waves, 2 blocks/CU (frozen) --------
__global__ __launch_bounds__(256, 2) void gemm_1wh(const u16* __restrict__ A,
                                                   const u16* __restrict__ Bt,
                                                   float* __restrict__ C,
                                                   int N, int K, int NT) {
  __shared__ u16 lsA[2][8192];    // 2 x 16KB (128 rows x 64 k)
  __shared__ u16 lsB[3][8192];    // 3 x 16KB
  const int tid = threadIdx.x;
  const int lane = tid & 63, w = tid >> 6;     // 4 waves
  const int wm = w >> 1, wn = w & 1;           // 2M x 2N
  const int l15 = lane & 15, l4 = lane >> 4;

  const int nwg = gridDim.x;                   // 512, %8==0
  const int cpx = nwg >> 3;
  const int bid = blockIdx.x;
  const int swz = (bid & 7) * cpx + (bid >> 3);
  const int bm = (swz & 15) * 128;             // 16 M-tiles (x-major)
  const int bn = (swz >> 4) * 128;             // 32 N-tiles

  auto stageA = [&](int unit, int slot, int kt) {
    int r = unit * 32 + (tid >> 3), cp = tid & 7;
    int scp = cp ^ (r & 7);
    gload16(A + (size_t)(bm + r) * K + kt * 64 + scp * 8,
            (char*)lsA[slot] + (unit * 256 + tid) * 16);
  };
  auto stageB = [&](int unit, int slot, int kt) {
    int r = unit * 32 + (tid >> 3), cp = tid & 7;
    int scp = cp ^ (r & 7);
    gload16(Bt + (size_t)(bn + r) * K + kt * 64 + scp * 8,
            (char*)lsB[slot] + (unit * 256 + tid) * 16);
  };
  auto rdA = [&](int slot, int mf, int ks) -> bf16x8 {
    int r = wm * 64 + mf * 16 + l15;
    int ch = (ks * 4 + l4) ^ (r & 7);
    return *(const bf16x8*)(lsA[slot] + r * 64 + ch * 8);
  };
  auto rdB = [&](int slot, int nf, int ks) -> bf16x8 {
    int r = wn * 64 + nf * 16 + l15;
    int ch = (ks * 4 + l4) ^ (r & 7);
    return *(const bf16x8*)(lsB[slot] + r * 64 + ch * 8);
  };

  f32x4 acc[4][4] = {};
  bf16x8 afA[4][2], bfr[4][2];

#pragma unroll
  for (int u = 0; u < 4; ++u) stageA(u, 0, 0);
#pragma unroll
  for (int u = 0; u < 4; ++u) stageB(u, 0, 0);
#pragma unroll
  for (int u = 0; u < 4; ++u) stageB(u, 1, 1);
  asm volatile("s_waitcnt vmcnt(4)" ::: "memory");
  __builtin_amdgcn_s_barrier();

  for (int t = 0; t < NT; ++t) {
    const int sA = t & 1, sB = t % 3;
    const int ktA = (t + 1 < NT) ? t + 1 : NT - 1;
    const int ktB = (t + 2 < NT) ? t + 2 : NT - 1;

#pragma unroll
    for (int mf = 0; mf < 4; ++mf)
#pragma unroll
      for (int ks = 0; ks < 2; ++ks) afA[mf][ks] = rdA(sA, mf, ks);
#pragma unroll
    for (int nf = 0; nf < 4; ++nf)
#pragma unroll
      for (int ks = 0; ks < 2; ++ks) bfr[nf][ks] = rdB(sB, nf, ks);
#pragma unroll
    for (int u = 0; u < 4; ++u) stageA(u, (t + 1) & 1, ktA);
#pragma unroll
    for (int u = 0; u < 4; ++u) stageB(u, (t + 2) % 3, ktB);
    __builtin_amdgcn_s_setprio(1);
#pragma unroll
    for (int nf = 0; nf < 4; ++nf)             // nf OUTER: consume in read order
#pragma unroll
      for (int mf = 0; mf < 4; ++mf) {
        acc[mf][nf] = __builtin_amdgcn_mfma_f32_16x16x32_bf16(afA[mf][0], bfr[nf][0], acc[mf][nf], 0, 0, 0);
        acc[mf][nf] = __builtin_amdgcn_mfma_f32_16x16x32_bf16(afA[mf][1], bfr[nf][1], acc[mf][nf], 0, 0, 0);
      }
    __builtin_amdgcn_s_setprio(0);
    asm volatile("s_waitcnt lgkmcnt(0)" ::: "memory");
    asm volatile("s_waitcnt vmcnt(4)" ::: "memory");   // tile t+1 resident
    __builtin_amdgcn_s_barrier();
  }

  asm volatile("s_waitcnt vmcnt(0)" ::: "memory");

#pragma unroll
  for (int mi = 0; mi < 4; ++mi)
#pragma unroll
    for (int ni = 0; ni < 4; ++ni) {
      int row = bm + wm * 64 + mi * 16 + l4 * 4;
      int col = bn + wn * 64 + ni * 16 + l15;
      float* p = C + (size_t)row * N + col;
      p[0] = acc[mi][ni][0];
      p[(size_t)N] = acc[mi][ni][1];
      p[2 * (size_t)N] = acc[mi][ni][2];
      p[3 * (size_t)N] = acc[mi][ni][3];
    }
}

// ---------------- RMSNorm + RoPE, 16 threads/vector x 8 elems (frozen, R19 form) --------
__global__ __launch_bounds__(256) void rope_kernel(const u16* __restrict__ qkv,
                                                   const float* __restrict__ cosb,
                                                   const float* __restrict__ sinb,
                                                   const float* __restrict__ qw,
                                                   const float* __restrict__ kw,
                                                   u16* __restrict__ Qo,
                                                   u16* __restrict__ Ko,
                                                   u16* __restrict__ Vn) {
  const int tid = threadIdx.x;
  const int v = blockIdx.x * 16 + (tid >> 4);   // vector index = t*48 + hid
  const int j = tid & 15;                       // 16 threads per vector
  const int t = v / 48, hid = v % 48;
  u16x8 raw = *(const u16x8*)(qkv + (size_t)v * 128 + j * 8);
  if (hid < NQ + NKV) {
    float xf[8];
    float ss = 0.f;
#pragma unroll
    for (int i = 0; i < 8; ++i) { xf[i] = bf2f(raw[i]); ss += xf[i] * xf[i]; }
    ss += __shfl_xor(ss, 1); ss += __shfl_xor(ss, 2);
    ss += __shfl_xor(ss, 4); ss += __shfl_xor(ss, 8);
    float inv = rsqrtf(ss * (1.0f / 128.0f) + 1e-6f);
    const float* wn = (hid < NQ) ? qw : kw;
    float4 w0 = *(const float4*)(wn + j * 8);
    float4 w1 = *(const float4*)(wn + j * 8 + 4);
    float wv[8] = {w0.x, w0.y, w0.z, w0.w, w1.x, w1.y, w1.z, w1.w};
    float n[8], p[8];
#pragma unroll
    for (int i = 0; i < 8; ++i) n[i] = xf[i] * inv * wv[i];
#pragma unroll
    for (int i = 0; i < 8; ++i) p[i] = __shfl_xor(n[i], 8);   // partner elems e+-64
    const float sgn = (j < 8) ? -1.f : 1.f;
    const float* cb = cosb + t * 128 + j * 8;
    const float* sb = sinb + t * 128 + j * 8;
    float4 c0 = *(const float4*)cb, c1 = *(const float4*)(cb + 4);
    float4 s0 = *(const float4*)sb, s1 = *(const float4*)(sb + 4);
    float cc[8] = {c0.x, c0.y, c0.z, c0.w, c1.x, c1.y, c1.z, c1.w};
    float sv[8] = {s0.x, s0.y, s0.z, s0.w, s1.x, s1.y, s1.z, s1.w};
    // fold 1/sqrt(128)*log2e into Q (softmax runs in log2 domain)
    const float scale = (hid < NQ) ? 0.08838834764831845f * 1.44269504088896341f : 1.0f;
    u16x8 o;
#pragma unroll
    for (int i = 0; i < 8; ++i)
      o[i] = f2bf((n[i] * cc[i] + sgn * p[i] * sv[i]) * scale);
    if (hid < NQ)
      *(u16x8*)(Qo + ((size_t)hid * T_SEQ + t) * 128 + j * 8) = o;
    else
      *(u16x8*)(Ko + ((size_t)(hid - NQ) * T_SEQ + t) * 128 + j * 8) = o;
  } else {
    *(u16x8*)(Vn + (size_t)t * 1024 + (hid - (NQ + NKV)) * 128 + j * 8) = raw;
  }
}

// ---------------- flash attention: 4 waves/block, QBLK=64, KVBLK=64 (frozen, R19 form) ----
__global__ __launch_bounds__(256) void attn_kernel(const u16* __restrict__ Q,
                                                   const u16* __restrict__ Kb,
                                                   const u16* __restrict__ Vt,
                                                   u16* __restrict__ O) {
  __shared__ u16 kls[2][64 * 128];   // 16KB per buf
  __shared__ u16 vls[2][128 * 64];   // 16KB per buf
  __shared__ u16 plds[4][16 * 72];   // per-wave P [16 q][64 k] pad to 72

  const int tid = threadIdx.x;
  const int lane = tid & 63, w = tid >> 6;
  const int l15 = lane & 15, l4 = lane >> 4;
  const int h = blockIdx.x;          // q head
  const int q0 = blockIdx.y * 64;    // block q base
  const int wq0 = q0 + w * 16;       // wave q base
  const int kvh = h >> 2;

  bf16x8 qf[4];
  {
    const u16* qrow = Q + ((size_t)h * T_SEQ + (wq0 + l15)) * DH;
    for (int ks = 0; ks < 4; ++ks)
      qf[ks] = *(const bf16x8*)(qrow + ks * 32 + l4 * 8);
  }

  f32x4 acc[8] = {};
  float m = -1e30f, lsum = 0.f;

  int ks0 = q0 - (WIN - 1); if (ks0 < 0) ks0 = 0;
  ks0 &= ~63;
  const int kend = q0;               // tile [q0, q0+63] covers the diagonal

  auto stage = [&](int b, int k0) {
#pragma unroll
    for (int c = 0; c < 4; ++c) {
      int base = w * 4096 + c * 1024;            // bytes in 16KB tile
      int idx = base / 16 + lane;                // 16B chunk index 0..1023
      {
        int row = idx >> 4;                      // K row (64 rows x 256B)
        int col = (idx & 15) ^ (row & 7);
        gload16(Kb + ((size_t)kvh * T_SEQ + k0 + row) * DH + col * 8,
                (char*)kls[b] + base);
      }
      {
        int d = idx >> 3;                        // V^T row (128 rows x 128B)
        int ch = (idx & 7) ^ (d & 7);
        gload16(Vt + ((size_t)kvh * DH + d) * T_SEQ + k0 + ch * 8,
                (char*)vls[b] + base);
      }
    }
  };

  stage(0, ks0);
  int buf = 0;
  for (int k0 = ks0; k0 <= kend; k0 += 64) {
    bool more = (k0 + 64 <= kend);
    if (more) stage(buf ^ 1, k0 + 64);
    if (more) { asm volatile("s_waitcnt vmcnt(8)" ::: "memory"); }
    else      { asm volatile("s_waitcnt vmcnt(0)" ::: "memory"); }
    __builtin_amdgcn_s_barrier();

    // wave skip: does [k0, k0+63] intersect [wq0-1023, wq0+15]?
    if (k0 <= wq0 + 15 && k0 + 63 >= wq0 - (WIN - 1)) {
      // ---- QK^T (swapped): S^T[k][q], A=K from LDS, B=Q regs ----
      f32x4 st[4];
      __builtin_amdgcn_s_setprio(1);
#pragma unroll
      for (int kh = 0; kh < 4; ++kh) {
        f32x4 s = {};
        int row = kh * 16 + l15;
        const char* kb = (const char*)kls[buf] + row * 256;
#pragma unroll
        for (int ks = 0; ks < 4; ++ks) {
          int chunk = (ks * 4 + l4) ^ (row & 7);
          bf16x8 kf = *(const bf16x8*)(kb + chunk * 16);
          s = __builtin_amdgcn_mfma_f32_16x16x32_bf16(kf, qf[ks], s, 0, 0, 0);
        }
        st[kh] = s;
      }
      __builtin_amdgcn_s_setprio(0);
      // ---- mask + online softmax in log2 domain (lane owns q = wq0+l15) ----
      const int q = wq0 + l15;
      float pv[4][4];
      float mx = -3e38f;
      if (k0 + 64 <= wq0 && k0 >= wq0 - 1008) {   // interior fast path
#pragma unroll
        for (int kh = 0; kh < 4; ++kh)
#pragma unroll
          for (int i = 0; i < 4; ++i) {
            pv[kh][i] = st[kh][i];
            mx = fmaxf(mx, pv[kh][i]);
          }
      } else {
#pragma unroll
        for (int kh = 0; kh < 4; ++kh)
#pragma unroll
          for (int i = 0; i < 4; ++i) {
            int k = k0 + kh * 16 + l4 * 4 + i;
            bool ok = ((k >> 2) <= (q >> 2)) && (q - k < WIN);
            float s = ok ? st[kh][i] : -3e38f;
            pv[kh][i] = s;
            mx = fmaxf(mx, s);
          }
      }
      mx = fmaxf(mx, __shfl_xor(mx, 16));
      mx = fmaxf(mx, __shfl_xor(mx, 32));
      if (!__all(mx <= m + 11.5f)) {    // defer-max (11.5 ~= 8 * log2e)
        float mn = fmaxf(m, mx);
        float sc = __builtin_amdgcn_exp2f(m - mn);
        m = mn;
        lsum *= sc;
#pragma unroll
        for (int nt = 0; nt < 8; ++nt)
#pragma unroll
          for (int i = 0; i < 4; ++i) acc[nt][i] *= sc;
      }
      float rs = 0.f;
#pragma unroll
      for (int kh = 0; kh < 4; ++kh)
#pragma unroll
        for (int i = 0; i < 4; ++i) {
          float p = __builtin_amdgcn_exp2f(pv[kh][i] - m);
          pv[kh][i] = p;
          rs += p;
        }
      rs += __shfl_xor(rs, 16);
      rs += __shfl_xor(rs, 32);
      lsum += rs;
      // ---- pack P -> per-wave LDS via v_cvt_pk_bf16_f32 ----
      u16* pw = plds[w];
#pragma unroll
      for (int kh = 0; kh < 4; ++kh) {
        unsigned int d0, d1;
        asm("v_cvt_pk_bf16_f32 %0, %1, %2" : "=v"(d0) : "v"(pv[kh][0]), "v"(pv[kh][1]));
        asm("v_cvt_pk_bf16_f32 %0, %1, %2" : "=v"(d1) : "v"(pv[kh][2]), "v"(pv[kh][3]));
        *(unsigned int*)(pw + l15 * 72 + kh * 16 + l4 * 4) = d0;
        *(unsigned int*)(pw + l15 * 72 + kh * 16 + l4 * 4 + 2) = d1;
      }
      bf16x8 pf0 = *(const bf16x8*)(pw + l15 * 72 + l4 * 8);
      bf16x8 pf1 = *(const bf16x8*)(pw + l15 * 72 + 32 + l4 * 8);
      // ---- PV: O^T += V^T * P^T (A = V^T from LDS, B = P), 2 K=32 halves ----
      __builtin_amdgcn_s_setprio(1);
#pragma unroll
      for (int nt = 0; nt < 8; ++nt) {
        int d = nt * 16 + l15;
        int ch0 = l4 ^ (d & 7);
        int ch1 = (4 + l4) ^ (d & 7);
        bf16x8 vf0 = *(const bf16x8*)((const char*)vls[buf] + d * 128 + ch0 * 16);
        bf16x8 vf1 = *(const bf16x8*)((const char*)vls[buf] + d * 128 + ch1 * 16);
        acc[nt] = __builtin_amdgcn_mfma_f32_16x16x32_bf16(vf0, pf0, acc[nt], 0, 0, 0);
        acc[nt] = __builtin_amdgcn_mfma_f32_16x16x32_bf16(vf1, pf1, acc[nt], 0, 0, 0);
      }
      __builtin_amdgcn_s_setprio(0);
    }
    __builtin_amdgcn_s_barrier();
    buf ^= 1;
  }

  // ---- epilogue ----
  float inv = 1.0f / lsum;
#pragma unroll
  for (int nt = 0; nt < 8; ++nt) {
    u16x4 o;
#pragma unroll
    for (int i = 0; i < 4; ++i) o[i] = f2bf(acc[nt][i] * inv);
    *(u16x4*)(O + (size_t)(wq0 + l15) * (NQ * DH) + h * DH + nt * 16 + l4 * 4) = o;
  }
}

extern "C" void kernel_launch(void* const* d_in, const int* in_sizes, int n_in,
                              void* d_out, int out_size, void* d_ws, size_t ws_size,
                              hipStream_t stream) {
  const float* hidden = (const float*)d_in[0];
  const float* cosb   = (const float*)d_in[1];
  const float* sinb   = (const float*)d_in[2];
  const float* w_qkv  = (const float*)d_in[3];
  const float* qnw    = (const float*)d_in[4];
  const float* knw    = (const float*)d_in[5];
  const float* w_o    = (const float*)d_in[6];
  float* out = (float*)d_out;
  char* ws = (char*)d_ws;

  u16*   wqkvT  = (u16*)(ws);                        // [0, 48M)
  u16*   hid_bf = (u16*)(ws + ((size_t)48 << 20));   // [48M, 64M)
  u16*   qkv_bf = (u16*)(ws + ((size_t)64 << 20));   // [64M, 88M) bf16 qkv (24MB)
  u16*   vn_bf  = (u16*)(ws + ((size_t)88 << 20));   // [88M, 92M) V natural (4MB)
  u16*   q_bf   = (u16*)(ws + ((size_t)112 << 20));  // 16MB
  u16*   k_bf   = (u16*)(ws + ((size_t)128 << 20));  // 4MB
  u16*   vt_bf  = (u16*)(ws + ((size_t)132 << 20));  // 4MB
  u16*   attn_bf= (u16*)(ws + ((size_t)48 << 20));   // reuse hid_bf region
  u16*   woT    = (u16*)(ws);                        // reuse wqkvT region

  f32_to_bf16<<<4096, 256, 0, stream>>>(hidden, hid_bf, T_SEQ * HID);
  transpose_f32_to_bf16<<<dim3(96, 64), dim3(16, 16), 0, stream>>>(w_qkv, wqkvT, HID, 6144);
  // gemm1: 2048x6144x4096, 128^2 tiles -> grid 16x48 = 768 = 3 blocks/CU, BK=32, bf16 out
  gemm_hw<true><<<768, 256, 0, stream>>>(hid_bf, wqkvT, qkv_bf, 6144, HID, 128);
  transpose_f32_to_bf16<<<dim3(64, 64), dim3(16, 16), 0, stream>>>(w_o, woT, NQ * DH, HID);
  rope_kernel<<<(T_SEQ * 48) / 16, 256, 0, stream>>>(qkv_bf, cosb, sinb, qnw, knw, q_bf, k_bf, vn_bf);
  v_transpose<<<dim3(32, 16), 256, 0, stream>>>(vn_bf, vt_bf);
  attn_kernel<<<dim3(NQ, T_SEQ / 64), 256, 0, stream>>>(q_bf, k_bf, vt_bf, attn_bf);
  // gemm2: 2048x4096x4096, 128^2 tiles -> grid 16x32 = 512 = 2 blocks/CU, f32 out
  gemm_1wh<<<512, 256, 0, stream>>>(attn_bf, woT, out, HID, NQ * DH, 64);
}

// Round 24
// 294.744 us; speedup vs baseline: 1.0862x; 1.0862x over previous
//
#include <hip/hip_runtime.h>
#include <hip/hip_bf16.h>

typedef unsigned short u16;
typedef __attribute__((ext_vector_type(8))) short bf16x8;
typedef __attribute__((ext_vector_type(4))) float f32x4;
typedef __attribute__((ext_vector_type(8))) u16 u16x8;
typedef __attribute__((ext_vector_type(4))) u16 u16x4;

#define T_SEQ 2048
#define HID 4096
#define NQ 32
#define NKV 8
#define DH 128
#define WIN 1024

__device__ __forceinline__ u16 f2bf(float f) {
  union { float f; unsigned int u; } v; v.f = f;
  unsigned int u = v.u;
  unsigned int r = (u + 0x7FFFu + ((u >> 16) & 1u)) >> 16;
  return (u16)r;
}
__device__ __forceinline__ float bf2f(u16 b) {
  union { unsigned int u; float f; } v; v.u = ((unsigned int)b) << 16;
  return v.f;
}

__device__ __forceinline__ void gload16(const void* g, void* l) {
  __builtin_amdgcn_global_load_lds(
      (const __attribute__((address_space(1))) unsigned int*)g,
      (__attribute__((address_space(3))) unsigned int*)l, 16, 0, 0);
}

// ---------------- elementwise f32 -> bf16 ----------------
__global__ __launch_bounds__(256) void f32_to_bf16(const float* __restrict__ in,
                                                   u16* __restrict__ out, int n) {
  int i = (blockIdx.x * 256 + threadIdx.x) * 8;
  if (i >= n) return;
  float4 a = *(const float4*)(in + i);
  float4 b = *(const float4*)(in + i + 4);
  u16x8 r;
  r[0] = f2bf(a.x); r[1] = f2bf(a.y); r[2] = f2bf(a.z); r[3] = f2bf(a.w);
  r[4] = f2bf(b.x); r[5] = f2bf(b.y); r[6] = f2bf(b.z); r[7] = f2bf(b.w);
  *(u16x8*)(out + i) = r;
}

// ---------------- tiled transpose f32 (R x C) -> bf16 (C x R), 64x64 float4 ----------------
__global__ __launch_bounds__(256) void transpose_f32_to_bf16(const float* __restrict__ in,
                                                             u16* __restrict__ out,
                                                             int R, int C) {
  __shared__ float tile[64][65];
  int c0 = blockIdx.x * 64, r0 = blockIdx.y * 64;
  int tx = threadIdx.x, ty = threadIdx.y;    // 16 x 16
#pragma unroll
  for (int i = 0; i < 64; i += 16) {
    float4 v = *(const float4*)(in + (size_t)(r0 + ty + i) * C + c0 + tx * 4);
    tile[ty + i][tx * 4 + 0] = v.x;
    tile[ty + i][tx * 4 + 1] = v.y;
    tile[ty + i][tx * 4 + 2] = v.z;
    tile[ty + i][tx * 4 + 3] = v.w;
  }
  __syncthreads();
#pragma unroll
  for (int i = 0; i < 64; i += 16) {
    u16x4 o;
#pragma unroll
    for (int j = 0; j < 4; ++j) o[j] = f2bf(tile[tx * 4 + j][ty + i]);
    *(u16x4*)(out + (size_t)(c0 + ty + i) * R + r0 + tx * 4) = o;
  }
}

// ---------------- bf16 transpose for V: Vn[2048][1024] -> Vt[1024][2048] ----------------
__global__ __launch_bounds__(256) void v_transpose(const u16* __restrict__ Vn,
                                                   u16* __restrict__ Vt) {
  __shared__ u16 tile[64][68];
  int tx = threadIdx.x & 15, ty = threadIdx.x >> 4;   // 16 x 16
  int t0 = blockIdx.x * 64, dh0 = blockIdx.y * 64;
#pragma unroll
  for (int i = 0; i < 64; i += 16) {
    u16x4 v = *(const u16x4*)(Vn + (size_t)(t0 + ty + i) * 1024 + dh0 + tx * 4);
    tile[ty + i][tx * 4 + 0] = v[0];
    tile[ty + i][tx * 4 + 1] = v[1];
    tile[ty + i][tx * 4 + 2] = v[2];
    tile[ty + i][tx * 4 + 3] = v[3];
  }
  __syncthreads();
#pragma unroll
  for (int i = 0; i < 64; i += 16) {
    u16x4 o;
#pragma unroll
    for (int j = 0; j < 4; ++j) o[j] = tile[tx * 4 + j][ty + i];
    *(u16x4*)(Vt + (size_t)(dh0 + ty + i) * 2048 + t0 + tx * 4) = o;
  }
}

// ---------------- gemm_1w: 256xBN GEMM, ONE barrier/tile (proven best, R18/R21 form) -----
// Structural endpoint of this template family (R22 closed the last lever):
// 48-MFMA cluster/window amortizes per-window overhead; 2 waves/SIMD;
// larger clusters > higher occupancy (cluster ladder: 8->30%, 16->35-38%,
// 48->48% MfmaUtil, occupancy-independent).
template <int NF, bool BF16OUT>
__global__ __launch_bounds__(512, 2) void gemm_1w(const u16* __restrict__ A,
                                                  const u16* __restrict__ Bt,
                                                  void* __restrict__ Cv,
                                                  int N, int K, int NT) {
  constexpr int HN = NF * 16;
  constexpr int BN = 4 * HN;
  constexpr int NB = BN / 64;
  __shared__ u16 lsA[2][16384];     // 2 x 32KB
  __shared__ u16 lsB[3][BN * 64];   // 3 x (BN*128B)
  const int tid = threadIdx.x;
  const int lane = tid & 63, w = tid >> 6;
  const int wm = w >> 1, wn = w & 1;           // 4M x 2N
  const int l15 = lane & 15, l4 = lane >> 4;

  const int nwg = gridDim.x;
  const int cpx = nwg >> 3;
  const int bid = blockIdx.x;
  const int swz = (bid & 7) * cpx + (bid >> 3);
  const int bm = (swz & 7) * 256;
  const int bn = (swz >> 3) * BN;

  auto stageA = [&](int unit, int slot, int kt) {
    int r = tid >> 3, cp = tid & 7;
    int scp = cp ^ (r & 7);
    gload16(A + (size_t)(bm + unit * 64 + r) * K + kt * 64 + scp * 8,
            (char*)lsA[slot] + (unit * 512 + tid) * 16);
  };
  auto stageB = [&](int unit, int slot, int kt) {
    int r = tid >> 3, cp = tid & 7;
    int scp = cp ^ (r & 7);
    gload16(Bt + (size_t)(bn + unit * 64 + r) * K + kt * 64 + scp * 8,
            (char*)lsB[slot] + (unit * 512 + tid) * 16);
  };
  auto rdA = [&](int slot, int mf, int ks) -> bf16x8 {
    int r = wm * 64 + mf * 16 + l15;
    int ch = (ks * 4 + l4) ^ (r & 7);
    return *(const bf16x8*)(lsA[slot] + r * 64 + ch * 8);
  };
  auto rdB = [&](int slot, int nf, int ks) -> bf16x8 {
    int r = wn * 2 * HN + nf * 16 + l15;
    int ch = (ks * 4 + l4) ^ (r & 7);
    return *(const bf16x8*)(lsB[slot] + r * 64 + ch * 8);
  };

#define WAIT_NB() do { if constexpr (NB == 3) asm volatile("s_waitcnt vmcnt(3)" ::: "memory"); \
                       else                   asm volatile("s_waitcnt vmcnt(2)" ::: "memory"); } while (0)

  f32x4 acc[4][2 * NF] = {};
  bf16x8 afA[4][2], bfr[2 * NF][2];

  stageA(0, 0, 0); stageA(1, 0, 0); stageA(2, 0, 0); stageA(3, 0, 0);
#pragma unroll
  for (int u = 0; u < NB; ++u) stageB(u, 0, 0);
#pragma unroll
  for (int u = 0; u < NB; ++u) stageB(u, 1, 1);
  WAIT_NB();
  __builtin_amdgcn_s_barrier();

  for (int t = 0; t < NT; ++t) {
    const int sA = t & 1, sB = t % 3;
    const int ktA = (t + 1 < NT) ? t + 1 : NT - 1;
    const int ktB = (t + 2 < NT) ? t + 2 : NT - 1;

#pragma unroll
    for (int mf = 0; mf < 4; ++mf)
#pragma unroll
      for (int ks = 0; ks < 2; ++ks) afA[mf][ks] = rdA(sA, mf, ks);
#pragma unroll
    for (int nf = 0; nf < 2 * NF; ++nf)
#pragma unroll
      for (int ks = 0; ks < 2; ++ks) bfr[nf][ks] = rdB(sB, nf, ks);
    stageA(0, (t + 1) & 1, ktA); stageA(1, (t + 1) & 1, ktA);
    stageA(2, (t + 1) & 1, ktA); stageA(3, (t + 1) & 1, ktA);
#pragma unroll
    for (int u = 0; u < NB; ++u) stageB(u, (t + 2) % 3, ktB);
    __builtin_amdgcn_s_setprio(1);
#pragma unroll
    for (int nf = 0; nf < 2 * NF; ++nf)        // nf OUTER: consume in read order
#pragma unroll
      for (int mf = 0; mf < 4; ++mf) {
        acc[mf][nf] = __builtin_amdgcn_mfma_f32_16x16x32_bf16(afA[mf][0], bfr[nf][0], acc[mf][nf], 0, 0, 0);
        acc[mf][nf] = __builtin_amdgcn_mfma_f32_16x16x32_bf16(afA[mf][1], bfr[nf][1], acc[mf][nf], 0, 0, 0);
      }
    __builtin_amdgcn_s_setprio(0);
    asm volatile("s_waitcnt lgkmcnt(0)" ::: "memory");
    WAIT_NB();
    __builtin_amdgcn_s_barrier();
  }

  asm volatile("s_waitcnt vmcnt(0)" ::: "memory");

#pragma unroll
  for (int mi = 0; mi < 4; ++mi)
#pragma unroll
    for (int ni = 0; ni < 2 * NF; ++ni) {
      int row = bm + wm * 64 + mi * 16 + l4 * 4;
      int col = bn + wn * 2 * HN + ni * 16 + l15;
      if constexpr (BF16OUT) {
        u16* dst = (u16*)Cv;
#pragma unroll
        for (int j = 0; j < 4; ++j)
          dst[(size_t)(row + j) * N + col] = f2bf(acc[mi][ni][j]);
      } else {
        float* p = (float*)Cv + (size_t)row * N + col;
        p[0] = acc[mi][ni][0];
        p[(size_t)N] = acc[mi][ni][1];
        p[2 * (size_t)N] = acc[mi][ni][2];
        p[3 * (size_t)N] = acc[mi][ni][3];
      }
    }
#undef WAIT_NB
}

// ---------------- gemm_1wh: 128x128 1-window GEMM, 4 waves, 2 blocks/CU (frozen) --------
__global__ __launch_bounds__(256, 2) void gemm_1wh(const u16* __restrict__ A,
                                                   const u16* __restrict__ Bt,
                                                   float* __restrict__ C,
                                                   int N, int K, int NT) {
  __shared__ u16 lsA[2][8192];    // 2 x 16KB (128 rows x 64 k)
  __shared__ u16 lsB[3][8192];    // 3 x 16KB
  const int tid = threadIdx.x;
  const int lane = tid & 63, w = tid >> 6;     // 4 waves
  const int wm = w >> 1, wn = w & 1;           // 2M x 2N
  const int l15 = lane & 15, l4 = lane >> 4;

  const int nwg = gridDim.x;                   // 512, %8==0
  const int cpx = nwg >> 3;
  const int bid = blockIdx.x;
  const int swz = (bid & 7) * cpx + (bid >> 3);
  const int bm = (swz & 15) * 128;             // 16 M-tiles (x-major)
  const int bn = (swz >> 4) * 128;             // 32 N-tiles

  auto stageA = [&](int unit, int slot, int kt) {
    int r = unit * 32 + (tid >> 3), cp = tid & 7;
    int scp = cp ^ (r & 7);
    gload16(A + (size_t)(bm + r) * K + kt * 64 + scp * 8,
            (char*)lsA[slot] + (unit * 256 + tid) * 16);
  };
  auto stageB = [&](int unit, int slot, int kt) {
    int r = unit * 32 + (tid >> 3), cp = tid & 7;
    int scp = cp ^ (r & 7);
    gload16(Bt + (size_t)(bn + r) * K + kt * 64 + scp * 8,
            (char*)lsB[slot] + (unit * 256 + tid) * 16);
  };
  auto rdA = [&](int slot, int mf, int ks) -> bf16x8 {
    int r = wm * 64 + mf * 16 + l15;
    int ch = (ks * 4 + l4) ^ (r & 7);
    return *(const bf16x8*)(lsA[slot] + r * 64 + ch * 8);
  };
  auto rdB = [&](int slot, int nf, int ks) -> bf16x8 {
    int r = wn * 64 + nf * 16 + l15;
    int ch = (ks * 4 + l4) ^ (r & 7);
    return *(const bf16x8*)(lsB[slot] + r * 64 + ch * 8);
  };

  f32x4 acc[4][4] = {};
  bf16x8 afA[4][2], bfr[4][2];

#pragma unroll
  for (int u = 0; u < 4; ++u) stageA(u, 0, 0);
#pragma unroll
  for (int u = 0; u < 4; ++u) stageB(u, 0, 0);
#pragma unroll
  for (int u = 0; u < 4; ++u) stageB(u, 1, 1);
  asm volatile("s_waitcnt vmcnt(4)" ::: "memory");
  __builtin_amdgcn_s_barrier();

  for (int t = 0; t < NT; ++t) {
    const int sA = t & 1, sB = t % 3;
    const int ktA = (t + 1 < NT) ? t + 1 : NT - 1;
    const int ktB = (t + 2 < NT) ? t + 2 : NT - 1;

#pragma unroll
    for (int mf = 0; mf < 4; ++mf)
#pragma unroll
      for (int ks = 0; ks < 2; ++ks) afA[mf][ks] = rdA(sA, mf, ks);
#pragma unroll
    for (int nf = 0; nf < 4; ++nf)
#pragma unroll
      for (int ks = 0; ks < 2; ++ks) bfr[nf][ks] = rdB(sB, nf, ks);
#pragma unroll
    for (int u = 0; u < 4; ++u) stageA(u, (t + 1) & 1, ktA);
#pragma unroll
    for (int u = 0; u < 4; ++u) stageB(u, (t + 2) % 3, ktB);
    __builtin_amdgcn_s_setprio(1);
#pragma unroll
    for (int nf = 0; nf < 4; ++nf)             // nf OUTER: consume in read order
#pragma unroll
      for (int mf = 0; mf < 4; ++mf) {
        acc[mf][nf] = __builtin_amdgcn_mfma_f32_16x16x32_bf16(afA[mf][0], bfr[nf][0], acc[mf][nf], 0, 0, 0);
        acc[mf][nf] = __builtin_amdgcn_mfma_f32_16x16x32_bf16(afA[mf][1], bfr[nf][1], acc[mf][nf], 0, 0, 0);
      }
    __builtin_amdgcn_s_setprio(0);
    asm volatile("s_waitcnt lgkmcnt(0)" ::: "memory");
    asm volatile("s_waitcnt vmcnt(4)" ::: "memory");   // tile t+1 resident
    __builtin_amdgcn_s_barrier();
  }

  asm volatile("s_waitcnt vmcnt(0)" ::: "memory");

#pragma unroll
  for (int mi = 0; mi < 4; ++mi)
#pragma unroll
    for (int ni = 0; ni < 4; ++ni) {
      int row = bm + wm * 64 + mi * 16 + l4 * 4;
      int col = bn + wn * 64 + ni * 16 + l15;
      float* p = C + (size_t)row * N + col;
      p[0] = acc[mi][ni][0];
      p[(size_t)N] = acc[mi][ni][1];
      p[2 * (size_t)N] = acc[mi][ni][2];
      p[3 * (size_t)N] = acc[mi][ni][3];
    }
}

// ---------------- RMSNorm + RoPE, 16 threads/vector x 8 elems (frozen, R19 form) --------
__global__ __launch_bounds__(256) void rope_kernel(const u16* __restrict__ qkv,
                                                   const float* __restrict__ cosb,
                                                   const float* __restrict__ sinb,
                                                   const float* __restrict__ qw,
                                                   const float* __restrict__ kw,
                                                   u16* __restrict__ Qo,
                                                   u16* __restrict__ Ko,
                                                   u16* __restrict__ Vn) {
  const int tid = threadIdx.x;
  const int v = blockIdx.x * 16 + (tid >> 4);   // vector index = t*48 + hid
  const int j = tid & 15;                       // 16 threads per vector
  const int t = v / 48, hid = v % 48;
  u16x8 raw = *(const u16x8*)(qkv + (size_t)v * 128 + j * 8);
  if (hid < NQ + NKV) {
    float xf[8];
    float ss = 0.f;
#pragma unroll
    for (int i = 0; i < 8; ++i) { xf[i] = bf2f(raw[i]); ss += xf[i] * xf[i]; }
    ss += __shfl_xor(ss, 1); ss += __shfl_xor(ss, 2);
    ss += __shfl_xor(ss, 4); ss += __shfl_xor(ss, 8);
    float inv = rsqrtf(ss * (1.0f / 128.0f) + 1e-6f);
    const float* wn = (hid < NQ) ? qw : kw;
    float4 w0 = *(const float4*)(wn + j * 8);
    float4 w1 = *(const float4*)(wn + j * 8 + 4);
    float wv[8] = {w0.x, w0.y, w0.z, w0.w, w1.x, w1.y, w1.z, w1.w};
    float n[8], p[8];
#pragma unroll
    for (int i = 0; i < 8; ++i) n[i] = xf[i] * inv * wv[i];
#pragma unroll
    for (int i = 0; i < 8; ++i) p[i] = __shfl_xor(n[i], 8);   // partner elems e+-64
    const float sgn = (j < 8) ? -1.f : 1.f;
    const float* cb = cosb + t * 128 + j * 8;
    const float* sb = sinb + t * 128 + j * 8;
    float4 c0 = *(const float4*)cb, c1 = *(const float4*)(cb + 4);
    float4 s0 = *(const float4*)sb, s1 = *(const float4*)(sb + 4);
    float cc[8] = {c0.x, c0.y, c0.z, c0.w, c1.x, c1.y, c1.z, c1.w};
    float sv[8] = {s0.x, s0.y, s0.z, s0.w, s1.x, s1.y, s1.z, s1.w};
    // fold 1/sqrt(128)*log2e into Q (softmax runs in log2 domain)
    const float scale = (hid < NQ) ? 0.08838834764831845f * 1.44269504088896341f : 1.0f;
    u16x8 o;
#pragma unroll
    for (int i = 0; i < 8; ++i)
      o[i] = f2bf((n[i] * cc[i] + sgn * p[i] * sv[i]) * scale);
    if (hid < NQ)
      *(u16x8*)(Qo + ((size_t)hid * T_SEQ + t) * 128 + j * 8) = o;
    else
      *(u16x8*)(Ko + ((size_t)(hid - NQ) * T_SEQ + t) * 128 + j * 8) = o;
  } else {
    *(u16x8*)(Vn + (size_t)t * 1024 + (hid - (NQ + NKV)) * 128 + j * 8) = raw;
  }
}

// ---------------- flash attention: 4 waves/block, QBLK=64, KVBLK=64 (frozen, R19 form) ----
__global__ __launch_bounds__(256) void attn_kernel(const u16* __restrict__ Q,
                                                   const u16* __restrict__ Kb,
                                                   const u16* __restrict__ Vt,
                                                   u16* __restrict__ O) {
  __shared__ u16 kls[2][64 * 128];   // 16KB per buf
  __shared__ u16 vls[2][128 * 64];   // 16KB per buf
  __shared__ u16 plds[4][16 * 72];   // per-wave P [16 q][64 k] pad to 72

  const int tid = threadIdx.x;
  const int lane = tid & 63, w = tid >> 6;
  const int l15 = lane & 15, l4 = lane >> 4;
  const int h = blockIdx.x;          // q head
  const int q0 = blockIdx.y * 64;    // block q base
  const int wq0 = q0 + w * 16;       // wave q base
  const int kvh = h >> 2;

  bf16x8 qf[4];
  {
    const u16* qrow = Q + ((size_t)h * T_SEQ + (wq0 + l15)) * DH;
    for (int ks = 0; ks < 4; ++ks)
      qf[ks] = *(const bf16x8*)(qrow + ks * 32 + l4 * 8);
  }

  f32x4 acc[8] = {};
  float m = -1e30f, lsum = 0.f;

  int ks0 = q0 - (WIN - 1); if (ks0 < 0) ks0 = 0;
  ks0 &= ~63;
  const int kend = q0;               // tile [q0, q0+63] covers the diagonal

  auto stage = [&](int b, int k0) {
#pragma unroll
    for (int c = 0; c < 4; ++c) {
      int base = w * 4096 + c * 1024;            // bytes in 16KB tile
      int idx = base / 16 + lane;                // 16B chunk index 0..1023
      {
        int row = idx >> 4;                      // K row (64 rows x 256B)
        int col = (idx & 15) ^ (row & 7);
        gload16(Kb + ((size_t)kvh * T_SEQ + k0 + row) * DH + col * 8,
                (char*)kls[b] + base);
      }
      {
        int d = idx >> 3;                        // V^T row (128 rows x 128B)
        int ch = (idx & 7) ^ (d & 7);
        gload16(Vt + ((size_t)kvh * DH + d) * T_SEQ + k0 + ch * 8,
                (char*)vls[b] + base);
      }
    }
  };

  stage(0, ks0);
  int buf = 0;
  for (int k0 = ks0; k0 <= kend; k0 += 64) {
    bool more = (k0 + 64 <= kend);
    if (more) stage(buf ^ 1, k0 + 64);
    if (more) { asm volatile("s_waitcnt vmcnt(8)" ::: "memory"); }
    else      { asm volatile("s_waitcnt vmcnt(0)" ::: "memory"); }
    __builtin_amdgcn_s_barrier();

    // wave skip: does [k0, k0+63] intersect [wq0-1023, wq0+15]?
    if (k0 <= wq0 + 15 && k0 + 63 >= wq0 - (WIN - 1)) {
      // ---- QK^T (swapped): S^T[k][q], A=K from LDS, B=Q regs ----
      f32x4 st[4];
      __builtin_amdgcn_s_setprio(1);
#pragma unroll
      for (int kh = 0; kh < 4; ++kh) {
        f32x4 s = {};
        int row = kh * 16 + l15;
        const char* kb = (const char*)kls[buf] + row * 256;
#pragma unroll
        for (int ks = 0; ks < 4; ++ks) {
          int chunk = (ks * 4 + l4) ^ (row & 7);
          bf16x8 kf = *(const bf16x8*)(kb + chunk * 16);
          s = __builtin_amdgcn_mfma_f32_16x16x32_bf16(kf, qf[ks], s, 0, 0, 0);
        }
        st[kh] = s;
      }
      __builtin_amdgcn_s_setprio(0);
      // ---- mask + online softmax in log2 domain (lane owns q = wq0+l15) ----
      const int q = wq0 + l15;
      float pv[4][4];
      float mx = -3e38f;
      if (k0 + 64 <= wq0 && k0 >= wq0 - 1008) {   // interior fast path
#pragma unroll
        for (int kh = 0; kh < 4; ++kh)
#pragma unroll
          for (int i = 0; i < 4; ++i) {
            pv[kh][i] = st[kh][i];
            mx = fmaxf(mx, pv[kh][i]);
          }
      } else {
#pragma unroll
        for (int kh = 0; kh < 4; ++kh)
#pragma unroll
          for (int i = 0; i < 4; ++i) {
            int k = k0 + kh * 16 + l4 * 4 + i;
            bool ok = ((k >> 2) <= (q >> 2)) && (q - k < WIN);
            float s = ok ? st[kh][i] : -3e38f;
            pv[kh][i] = s;
            mx = fmaxf(mx, s);
          }
      }
      mx = fmaxf(mx, __shfl_xor(mx, 16));
      mx = fmaxf(mx, __shfl_xor(mx, 32));
      if (!__all(mx <= m + 11.5f)) {    // defer-max (11.5 ~= 8 * log2e)
        float mn = fmaxf(m, mx);
        float sc = __builtin_amdgcn_exp2f(m - mn);
        m = mn;
        lsum *= sc;
#pragma unroll
        for (int nt = 0; nt < 8; ++nt)
#pragma unroll
          for (int i = 0; i < 4; ++i) acc[nt][i] *= sc;
      }
      float rs = 0.f;
#pragma unroll
      for (int kh = 0; kh < 4; ++kh)
#pragma unroll
        for (int i = 0; i < 4; ++i) {
          float p = __builtin_amdgcn_exp2f(pv[kh][i] - m);
          pv[kh][i] = p;
          rs += p;
        }
      rs += __shfl_xor(rs, 16);
      rs += __shfl_xor(rs, 32);
      lsum += rs;
      // ---- pack P -> per-wave LDS via v_cvt_pk_bf16_f32 ----
      u16* pw = plds[w];
#pragma unroll
      for (int kh = 0; kh < 4; ++kh) {
        unsigned int d0, d1;
        asm("v_cvt_pk_bf16_f32 %0, %1, %2" : "=v"(d0) : "v"(pv[kh][0]), "v"(pv[kh][1]));
        asm("v_cvt_pk_bf16_f32 %0, %1, %2" : "=v"(d1) : "v"(pv[kh][2]), "v"(pv[kh][3]));
        *(unsigned int*)(pw + l15 * 72 + kh * 16 + l4 * 4) = d0;
        *(unsigned int*)(pw + l15 * 72 + kh * 16 + l4 * 4 + 2) = d1;
      }
      bf16x8 pf0 = *(const bf16x8*)(pw + l15 * 72 + l4 * 8);
      bf16x8 pf1 = *(const bf16x8*)(pw + l15 * 72 + 32 + l4 * 8);
      // ---- PV: O^T += V^T * P^T (A = V^T from LDS, B = P), 2 K=32 halves ----
      __builtin_amdgcn_s_setprio(1);
#pragma unroll
      for (int nt = 0; nt < 8; ++nt) {
        int d = nt * 16 + l15;
        int ch0 = l4 ^ (d & 7);
        int ch1 = (4 + l4) ^ (d & 7);
        bf16x8 vf0 = *(const bf16x8*)((const char*)vls[buf] + d * 128 + ch0 * 16);
        bf16x8 vf1 = *(const bf16x8*)((const char*)vls[buf] + d * 128 + ch1 * 16);
        acc[nt] = __builtin_amdgcn_mfma_f32_16x16x32_bf16(vf0, pf0, acc[nt], 0, 0, 0);
        acc[nt] = __builtin_amdgcn_mfma_f32_16x16x32_bf16(vf1, pf1, acc[nt], 0, 0, 0);
      }
      __builtin_amdgcn_s_setprio(0);
    }
    __builtin_amdgcn_s_barrier();
    buf ^= 1;
  }

  // ---- epilogue ----
  float inv = 1.0f / lsum;
#pragma unroll
  for (int nt = 0; nt < 8; ++nt) {
    u16x4 o;
#pragma unroll
    for (int i = 0; i < 4; ++i) o[i] = f2bf(acc[nt][i] * inv);
    *(u16x4*)(O + (size_t)(wq0 + l15) * (NQ * DH) + h * DH + nt * 16 + l4 * 4) = o;
  }
}

extern "C" void kernel_launch(void* const* d_in, const int* in_sizes, int n_in,
                              void* d_out, int out_size, void* d_ws, size_t ws_size,
                              hipStream_t stream) {
  const float* hidden = (const float*)d_in[0];
  const float* cosb   = (const float*)d_in[1];
  const float* sinb   = (const float*)d_in[2];
  const float* w_qkv  = (const float*)d_in[3];
  const float* qnw    = (const float*)d_in[4];
  const float* knw    = (const float*)d_in[5];
  const float* w_o    = (const float*)d_in[6];
  float* out = (float*)d_out;
  char* ws = (char*)d_ws;

  u16*   wqkvT  = (u16*)(ws);                        // [0, 48M)
  u16*   hid_bf = (u16*)(ws + ((size_t)48 << 20));   // [48M, 64M)
  u16*   qkv_bf = (u16*)(ws + ((size_t)64 << 20));   // [64M, 88M) bf16 qkv (24MB)
  u16*   vn_bf  = (u16*)(ws + ((size_t)88 << 20));   // [88M, 92M) V natural (4MB)
  u16*   q_bf   = (u16*)(ws + ((size_t)112 << 20));  // 16MB
  u16*   k_bf   = (u16*)(ws + ((size_t)128 << 20));  // 4MB
  u16*   vt_bf  = (u16*)(ws + ((size_t)132 << 20));  // 4MB
  u16*   attn_bf= (u16*)(ws + ((size_t)48 << 20));   // reuse hid_bf region
  u16*   woT    = (u16*)(ws);                        // reuse wqkvT region

  f32_to_bf16<<<4096, 256, 0, stream>>>(hidden, hid_bf, T_SEQ * HID);
  transpose_f32_to_bf16<<<dim3(96, 64), dim3(16, 16), 0, stream>>>(w_qkv, wqkvT, HID, 6144);
  // gemm1: 2048x6144x4096, BN=192 -> grid 8x32 = 256 (full fill), bf16 out, 1-barrier/tile
  gemm_1w<3, true><<<256, 512, 0, stream>>>(hid_bf, wqkvT, qkv_bf, 6144, HID, 64);
  transpose_f32_to_bf16<<<dim3(64, 64), dim3(16, 16), 0, stream>>>(w_o, woT, NQ * DH, HID);
  rope_kernel<<<(T_SEQ * 48) / 16, 256, 0, stream>>>(qkv_bf, cosb, sinb, qnw, knw, q_bf, k_bf, vn_bf);
  v_transpose<<<dim3(32, 16), 256, 0, stream>>>(vn_bf, vt_bf);
  attn_kernel<<<dim3(NQ, T_SEQ / 64), 256, 0, stream>>>(q_bf, k_bf, vt_bf, attn_bf);
  // gemm2: 2048x4096x4096, 128^2 tiles -> grid 16x32 = 512 = 2 blocks/CU, f32 out
  gemm_1wh<<<512, 256, 0, stream>>>(attn_bf, woT, out, HID, NQ * DH, 64);
}